// Round 13
// baseline (108.927 us; speedup 1.0000x reference)
//
#include <hip/hip_runtime.h>
#include <hip/hip_bf16.h>
#include <hip/hip_fp16.h>
#include <math.h>

#define T_TOKENS 16384
#define DDIM 2048
#define NEXP 64
#define REFINE_TAU 4e-3f

typedef _Float16 f16x8 __attribute__((ext_vector_type(8)));
typedef float f32x4 __attribute__((ext_vector_type(4)));

// ---------------- Kernel 0: W fp32 -> fp16 B-fragment panel ----------------
// [slice(8)][g(4)][ks(8)][lane(64)][8]: slice=k>>8, g=r>>4, ks=(k>>5)&7,
// lane=((k>>3)&3)*16+(r&15), j=k&7.  (frag mapping verified R4-R12)
__global__ __launch_bounds__(256)
void prep_w(const float* __restrict__ W, _Float16* __restrict__ pw) {
    const int t  = blockIdx.x * 256 + threadIdx.x;   // 0..16383
    const int r  = t >> 8;
    const int kc = (t & 255) * 8;
    const float* wp = &W[(size_t)r * DDIM + kc];
    const float4 a = *(const float4*)wp;
    const float4 b = *(const float4*)(wp + 4);
    const float f[8] = { a.x, a.y, a.z, a.w, b.x, b.y, b.z, b.w };
    f16x8 h;
#pragma unroll
    for (int j = 0; j < 8; ++j) h[j] = (_Float16)f[j];
    const int slice = kc >> 8;
    const int ks    = (kc >> 5) & 7;
    const int g     = r >> 4;
    const int lane  = (((kc >> 3) & 3) << 4) | (r & 15);
    *(f16x8*)&pw[((((size_t)slice * 4 + g) * 8 + ks) * 64 + lane) * 8] = h;
}

// ---------------- Kernel 1: x fp32 -> fp16 A-fragment panel (pure stream) ----------------
// frag f = (tile*8 + slice)*8 + ks; xp[f][lane][8]:
// element = x[tile*16 + (lane&15)][slice*256 + ks*32 + (lane>>4)*8 + j]
__global__ __launch_bounds__(256)
void x_cvt(const float* __restrict__ x, _Float16* __restrict__ xp) {
    const int tid = threadIdx.x;
    const int l   = tid & 63;
    const int w   = tid >> 6;
    const int gw  = blockIdx.x * 4 + w;          // 0..8191
#pragma unroll
    for (int it = 0; it < 8; ++it) {
        const int f     = gw * 8 + it;           // 0..65535
        const int tile  = f >> 6;
        const int slice = (f >> 3) & 7;
        const int ks    = f & 7;
        const int row   = tile * 16 + (l & 15);
        const int kb    = slice * 256 + ks * 32 + ((l >> 4) << 3);
        const float4 a = *(const float4*)&x[(size_t)row * DDIM + kb];
        const float4 b = *(const float4*)&x[(size_t)row * DDIM + kb + 4];
        f16x8 h;
        h[0] = (_Float16)a.x; h[1] = (_Float16)a.y;
        h[2] = (_Float16)a.z; h[3] = (_Float16)a.w;
        h[4] = (_Float16)b.x; h[5] = (_Float16)b.y;
        h[6] = (_Float16)b.z; h[7] = (_Float16)b.w;
        *(f16x8*)&xp[(size_t)f * 512 + l * 8] = h;   // coalesced 1 KB per wave
    }
}

// ---------------- Kernel 2: frag-panel GEMM + fused top-2 (TLP-dumb hot loop) ----------------
__device__ __forceinline__ bool better(double va, int ia, double vb, int ib) {
    return (va > vb) || (va == vb && ia < ib);
}
__device__ __forceinline__ double dot_f64(const float* __restrict__ xrow,
                                          const float* __restrict__ wr, int lane) {
    double sd = 0.0;
    for (int d = lane; d < DDIM; d += 64)
        sd = fma((double)xrow[d], (double)wr[d], sd);
#pragma unroll
    for (int off = 32; off >= 1; off >>= 1) sd += __shfl_xor(sd, off);
    return sd;
}

__global__ __launch_bounds__(512)
void gate_fused(const _Float16* __restrict__ xp,
                const _Float16* __restrict__ pw,
                const float* __restrict__ x,
                const float* __restrict__ W,
                float* __restrict__ out) {
    __shared__ float part[8][NEXP][17];    // 34.8 KB -> 4 blocks/CU, 32 waves/CU

    const int tid  = threadIdx.x;
    const int lane = tid & 63;
    const int w    = tid >> 6;             // K-slice 0..7
    const int tile = blockIdx.x;           // 16-token tile
    const int tokb = tile * 16;

    const _Float16* ap = xp + ((size_t)(tile * 8 + w) * 8) * 512 + lane * 8;
    const _Float16* bp = pw + ((size_t)w * 4 * 8) * 512 + lane * 8;

    f32x4 acc[4] = { {0,0,0,0}, {0,0,0,0}, {0,0,0,0}, {0,0,0,0} };

#pragma unroll
    for (int ks = 0; ks < 8; ++ks) {
        const f16x8 af = *(const f16x8*)(ap + ks * 512);
#pragma unroll
        for (int g = 0; g < 4; ++g) {
            const f16x8 bf = *(const f16x8*)(bp + (g * 8 + ks) * 512);
            acc[g] = __builtin_amdgcn_mfma_f32_16x16x32_f16(af, bf, acc[g], 0, 0, 0);
        }
    }

    // C layout (R12-verified): row=(lane>>4)*4+j = token-in-16, col=lane&15 = expert-in-group
#pragma unroll
    for (int g = 0; g < 4; ++g)
#pragma unroll
        for (int j = 0; j < 4; ++j)
            part[w][g * 16 + (lane & 15)][((lane >> 4) << 2) + j] = acc[g][j];
    __syncthreads();

    // ---- fused epilogue (R7-verified): wave w owns 2 tokens; fixed-order K reduce ----
    float* __restrict__ outw = out;
    float* __restrict__ outi = out + (size_t)T_TOKENS * 2;

#pragma unroll 1
    for (int t = 0; t < 2; ++t) {
        const int lt  = w * 2 + t;
        const int tok = tokb + lt;
        const float l = (((part[0][lane][lt] + part[1][lane][lt])
                        + (part[2][lane][lt] + part[3][lane][lt]))
                       + ((part[4][lane][lt] + part[5][lane][lt])
                        + (part[6][lane][lt] + part[7][lane][lt])));

        float v1 = l; int i1 = lane;
#pragma unroll
        for (int off = 32; off >= 1; off >>= 1) {
            const float ov = __shfl_xor(v1, off);
            const int   oi = __shfl_xor(i1, off);
            if (ov > v1 || (ov == v1 && oi < i1)) { v1 = ov; i1 = oi; }
        }
        float v2 = (lane == i1) ? -INFINITY : l; int i2 = lane;
#pragma unroll
        for (int off = 32; off >= 1; off >>= 1) {
            const float ov = __shfl_xor(v2, off);
            const int   oi = __shfl_xor(i2, off);
            if (ov > v2 || (ov == v2 && oi < i2)) { v2 = ov; i2 = oi; }
        }
        float v3 = (lane == i1 || lane == i2) ? -INFINITY : l; int i3 = lane;
#pragma unroll
        for (int off = 32; off >= 1; off >>= 1) {
            const float ov = __shfl_xor(v3, off);
            const int   oi = __shfl_xor(i3, off);
            if (ov > v3 || (ov == v3 && oi < i3)) { v3 = ov; i3 = oi; }
        }

        const float p = expf(l - v1);
        float s = p;
#pragma unroll
        for (int off = 32; off >= 1; off >>= 1) s += __shfl_xor(s, off);

        int iA = i1, iB = i2;
        if ((v1 - v2) < REFINE_TAU || (v2 - v3) < REFINE_TAU) {
            const float* __restrict__ xrow = x + (size_t)tok * DDIM;
            double La = dot_f64(xrow, W + (size_t)i1 * DDIM, lane);
            double Lb = dot_f64(xrow, W + (size_t)i2 * DDIM, lane);
            double Lc = dot_f64(xrow, W + (size_t)i3 * DDIM, lane);
            int ia = i1, ib = i2, ic = i3;
            if (!better(La, ia, Lb, ib)) { double tv = La; La = Lb; Lb = tv; int ti = ia; ia = ib; ib = ti; }
            if (!better(Lb, ib, Lc, ic)) { double tv = Lb; Lb = Lc; Lc = tv; int ti = ib; ib = ic; ic = ti; }
            if (!better(La, ia, Lb, ib)) { double tv = La; La = Lb; Lb = tv; int ti = ia; ia = ib; ib = ti; }
            iA = ia; iB = ib;
        }

        const float pA = __shfl(p, iA);
        const float pB = __shfl(p, iB);
        const float pa_ = pA / s;
        const float pb_ = pB / s;
        const float inv = 1.0f / (pa_ + pb_ + 1e-9f);

        if (lane == 0) {
            const size_t tg2 = (size_t)tok;
            outw[tg2 * 2]     = pa_ * inv;
            outw[tg2 * 2 + 1] = pb_ * inv;
            outi[tg2 * 2]     = (float)iA;
            outi[tg2 * 2 + 1] = (float)iB;
        }
    }
}

extern "C" void kernel_launch(void* const* d_in, const int* in_sizes, int n_in,
                              void* d_out, int out_size, void* d_ws, size_t ws_size,
                              hipStream_t stream) {
    const float* x = (const float*)d_in[0];
    const float* W = (const float*)d_in[1];
    float* out = (float*)d_out;

    _Float16* pw = (_Float16*)d_ws;                          // 256 KB W frag panel
    _Float16* xp = (_Float16*)((char*)d_ws + (1 << 20));     // 64 MB x frag panel

    prep_w<<<64, 256, 0, stream>>>(W, pw);
    x_cvt<<<2048, 256, 0, stream>>>(x, xp);
    gate_fused<<<1024, 512, 0, stream>>>(xp, pw, x, W, out);
}

// Round 14
// 78.130 us; speedup vs baseline: 1.3942x; 1.3942x over previous
//
#include <hip/hip_runtime.h>
#include <hip/hip_bf16.h>
#include <hip/hip_fp16.h>
#include <math.h>

#define T_TOKENS 16384
#define DDIM 2048
#define NEXP 64
#define REFINE_TAU 4e-3f
#define KSPLIT 8
#define KPW (DDIM / KSPLIT)       // 256 k per wave
#define NCHW (KPW / 32)           // 8 chunks of 32-k per wave
#define BLK_TOK 16
#define NBLK (T_TOKENS / BLK_TOK) // 1024 blocks

typedef _Float16 f16x8 __attribute__((ext_vector_type(8)));
typedef float f32x4 __attribute__((ext_vector_type(4)));

// ---------------- Kernel 0: W fp32 -> fp16 fragment-ordered panel ----------------
// (r,k) -> pw[((g*64 + ks)*64 + lane)*8 + j], g=r>>4, ks=k>>5,
// lane=((k>>3)&3)*16 + (r&15), j=k&7.  (A-frag mapping, verified R4-R13.)
__global__ __launch_bounds__(256)
void prep_w(const float* __restrict__ W, _Float16* __restrict__ pw) {
    const int t  = blockIdx.x * 256 + threadIdx.x;   // 0..16383
    const int r  = t >> 8;
    const int kc = (t & 255) * 8;
    const float* wp = &W[(size_t)r * DDIM + kc];
    const float4 a = *(const float4*)wp;
    const float4 b = *(const float4*)(wp + 4);
    const float f[8] = { a.x, a.y, a.z, a.w, b.x, b.y, b.z, b.w };
    f16x8 h;
#pragma unroll
    for (int j = 0; j < 8; ++j) h[j] = (_Float16)f[j];
    const int g = r >> 4, ks = kc >> 5;
    const int lane = (((kc >> 3) & 3) << 4) + (r & 15);
    *(f16x8*)&pw[(((size_t)g * 64 + ks) * 64 + lane) * 8] = h;
}

// ---------------- Kernel 1: gate GEMM + fused top-2 (R7 structure, fp16 single) ----------------
__device__ __forceinline__ bool better(double va, int ia, double vb, int ib) {
    return (va > vb) || (va == vb && ia < ib);
}
__device__ __forceinline__ double dot_f64(const float* __restrict__ xrow,
                                          const float* __restrict__ wr, int lane) {
    double sd = 0.0;
    for (int d = lane; d < DDIM; d += 64)
        sd = fma((double)xrow[d], (double)wr[d], sd);
#pragma unroll
    for (int off = 32; off >= 1; off >>= 1) sd += __shfl_xor(sd, off);
    return sd;
}

#define LOADX(slot, c) do { \
    const float* p_ = xsrc + (size_t)(c) * 32; \
    xr[slot][0] = *(const float4*)p_; \
    xr[slot][1] = *(const float4*)(p_ + 4); \
} while (0)

#define LOADP(buf, c) do { \
    _Pragma("unroll") \
    for (int mt_ = 0; mt_ < 4; ++mt_) \
        pa[buf][mt_] = *(const f16x8*)&pw[pbase + (size_t)(c) * 512 + (size_t)mt_ * 32768]; \
} while (0)

#define CHUNK(slot, buf) do { \
    f16x8 af_; \
    af_[0] = (_Float16)xr[slot][0].x; af_[1] = (_Float16)xr[slot][0].y; \
    af_[2] = (_Float16)xr[slot][0].z; af_[3] = (_Float16)xr[slot][0].w; \
    af_[4] = (_Float16)xr[slot][1].x; af_[5] = (_Float16)xr[slot][1].y; \
    af_[6] = (_Float16)xr[slot][1].z; af_[7] = (_Float16)xr[slot][1].w; \
    _Pragma("unroll") \
    for (int mt_ = 0; mt_ < 4; ++mt_) \
        acc[mt_] = __builtin_amdgcn_mfma_f32_16x16x32_f16(pa[buf][mt_], af_, acc[mt_], 0, 0, 0); \
} while (0)

__global__ __launch_bounds__(512, 4)   // 128-VGPR cap: room for the full pipeline working set
void gate_fused(const float* __restrict__ x,
                const _Float16* __restrict__ pw,
                const float* __restrict__ W,
                float* __restrict__ out) {
    __shared__ float part[KSPLIT][NEXP][17];   // 34.8 KB

    const int tid  = threadIdx.x;
    const int lane = tid & 63;
    const int w    = tid >> 6;                 // K-slice 0..7
    const int tokb = blockIdx.x * BLK_TOK;

    // x B-frag source: token tokb+(lane&15), k = w*256 + ks*32 + (lane>>4)*8
    const float* xsrc = x + (size_t)(tokb + (lane & 15)) * DDIM
                          + (size_t)w * KPW + ((lane >> 4) << 3);
    // W A-frag panel base for this wave's K-slice: (w*8 + c)*512 + lane*8, mt stride 32768
    const size_t pbase = (size_t)w * 4096 + (size_t)lane * 8;

    f32x4 acc[4] = { {0,0,0,0}, {0,0,0,0}, {0,0,0,0}, {0,0,0,0} };
    float4 xr[3][2];
    f16x8 pa[2][4];

    // prologue: 3-deep x prefetch, 1-deep panel prefetch
    LOADX(0, 0); LOADX(1, 1); LOADX(2, 2);
    LOADP(0, 0);

#pragma unroll
    for (int c = 0; c < NCHW; ++c) {
        if (c + 1 < NCHW) LOADP((c + 1) & 1, c + 1);
        CHUNK(c % 3, c & 1);
        if (c + 3 < NCHW) LOADX((c + 3) % 3, c + 3);
    }

    // ---- partials -> LDS (C: col=lane&15=token, row=(lane>>4)*4+j=expert-in-tile; verified) ----
#pragma unroll
    for (int mt = 0; mt < 4; ++mt)
#pragma unroll
        for (int j = 0; j < 4; ++j) {
            const int e = mt * 16 + ((lane >> 4) << 2) + j;
            part[w][e][lane & 15] = acc[mt][j];
        }
    __syncthreads();

    // ---- epilogue: wave w owns 2 tokens; fixed-order K reduction (deterministic) ----
    float* __restrict__ outw = out;
    float* __restrict__ outi = out + (size_t)T_TOKENS * 2;

#pragma unroll 1
    for (int t = 0; t < 2; ++t) {
        const int lt  = w * 2 + t;
        const int tok = tokb + lt;
        const float l = (((part[0][lane][lt] + part[1][lane][lt])
                        + (part[2][lane][lt] + part[3][lane][lt]))
                       + ((part[4][lane][lt] + part[5][lane][lt])
                        + (part[6][lane][lt] + part[7][lane][lt])));

        float v1 = l; int i1 = lane;
#pragma unroll
        for (int off = 32; off >= 1; off >>= 1) {
            const float ov = __shfl_xor(v1, off);
            const int   oi = __shfl_xor(i1, off);
            if (ov > v1 || (ov == v1 && oi < i1)) { v1 = ov; i1 = oi; }
        }
        float v2 = (lane == i1) ? -INFINITY : l; int i2 = lane;
#pragma unroll
        for (int off = 32; off >= 1; off >>= 1) {
            const float ov = __shfl_xor(v2, off);
            const int   oi = __shfl_xor(i2, off);
            if (ov > v2 || (ov == v2 && oi < i2)) { v2 = ov; i2 = oi; }
        }
        float v3 = (lane == i1 || lane == i2) ? -INFINITY : l; int i3 = lane;
#pragma unroll
        for (int off = 32; off >= 1; off >>= 1) {
            const float ov = __shfl_xor(v3, off);
            const int   oi = __shfl_xor(i3, off);
            if (ov > v3 || (ov == v3 && oi < i3)) { v3 = ov; i3 = oi; }
        }

        const float p = expf(l - v1);
        float s = p;
#pragma unroll
        for (int off = 32; off >= 1; off >>= 1) s += __shfl_xor(s, off);

        int iA = i1, iB = i2;
        if ((v1 - v2) < REFINE_TAU || (v2 - v3) < REFINE_TAU) {
            const float* __restrict__ xrow = x + (size_t)tok * DDIM;
            double La = dot_f64(xrow, W + (size_t)i1 * DDIM, lane);
            double Lb = dot_f64(xrow, W + (size_t)i2 * DDIM, lane);
            double Lc = dot_f64(xrow, W + (size_t)i3 * DDIM, lane);
            int ia = i1, ib = i2, ic = i3;
            if (!better(La, ia, Lb, ib)) { double tv = La; La = Lb; Lb = tv; int ti = ia; ia = ib; ib = ti; }
            if (!better(Lb, ib, Lc, ic)) { double tv = Lb; Lb = Lc; Lc = tv; int ti = ib; ib = ic; ic = ti; }
            if (!better(La, ia, Lb, ib)) { double tv = La; La = Lb; Lb = tv; int ti = ia; ia = ib; ib = ti; }
            iA = ia; iB = ib;
        }

        const float pA = __shfl(p, iA);
        const float pB = __shfl(p, iB);
        const float pa_ = pA / s;
        const float pb_ = pB / s;
        const float inv = 1.0f / (pa_ + pb_ + 1e-9f);

        if (lane == 0) {
            const size_t tg2 = (size_t)tok;
            outw[tg2 * 2]     = pa_ * inv;
            outw[tg2 * 2 + 1] = pb_ * inv;
            outi[tg2 * 2]     = (float)iA;
            outi[tg2 * 2 + 1] = (float)iB;
        }
    }
}

extern "C" void kernel_launch(void* const* d_in, const int* in_sizes, int n_in,
                              void* d_out, int out_size, void* d_ws, size_t ws_size,
                              hipStream_t stream) {
    const float* x = (const float*)d_in[0];
    const float* W = (const float*)d_in[1];
    float* out = (float*)d_out;
    _Float16* pw = (_Float16*)d_ws;                 // 256 KB fp16 frag panel

    prep_w<<<NEXP * DDIM / 8 / 256, 256, 0, stream>>>(W, pw);
    gate_fused<<<NBLK, 512, 0, stream>>>(x, pw, W, out);
}